// Round 2
// baseline (180.990 us; speedup 1.0000x reference)
//
#include <hip/hip_runtime.h>

// FeatureRefine, MI355X/gfx950 — round 7.
// R6 post-mortem: explicit load arrays were re-sunk by the scheduler (VGPR
// stayed 60, dur 67.5us unchanged). Occupancy 35%, FETCH 201MB of 720MB
// logical random-gather traffic (plane 8MB vs 4MB L2/XCD).
// Changes:
//  1. fr_refine v3 — CHANNEL-SPLIT: each block does 32px x 128ch (uint2
//     gathers, 8B/lane). LDS 16KB, __launch_bounds__(256,8) -> 8 blocks/CU
//     (100% occupancy target). sched_barrier(0) pins all 11 gather loads
//     before the FMA chain. XCD = (batch, c-half) -> per-XCD gather working
//     set = 4MB = L2 size (was 8MB) -> FETCH should drop.
//  2. transpose v4 — 256hw x 128c tiles (66.5KB LDS, 2 blocks/CU) so read
//     phase of one block overlaps write phase of the other; geo fused in
//     ch==0 blocks only.

#define N_ 4
#define C_ 256
#define H_ 128
#define W_ 128
#define HW_ (H_ * W_)
#define SCALE 0.125f

typedef unsigned int uint32;

__device__ __forceinline__ uint32 f2bf(float f) {
    uint32 u = __float_as_uint(f);
    u = (u + 0x7FFF + ((u >> 16) & 1)) >> 16;   // RNE
    return u;
}
__device__ __forceinline__ float blo(uint32 u) { return __uint_as_float(u << 16); }
__device__ __forceinline__ float bhi(uint32 u) { return __uint_as_float(u & 0xFFFF0000u); }

// ---------- Pass 0: NCHW fp32 -> NHWC bf16 (packed ch-pairs) + fused geo ----------
// Tile 256 hw x 128 ch (one c-half). 1024 thr / 16 waves; 4 cpairs per wave.
// LDS [64 cpair][256 hw + pad] = 66.5 KB -> 2 blocks/CU (phases overlap).
// Reads: float4 = 1KB contiguous per wave-load, 8 in flight.
// Writes: per wave one 256B span per row (half-row of NHWC words).
__global__ __launch_bounds__(1024, 8) void nchw2nhwc_geo(const float* __restrict__ in,
                                                         const float* __restrict__ bb,
                                                         uint32* __restrict__ outU,
                                                         uint32* __restrict__ geoG)
{
    __shared__ uint32 tile[64 * 260];
    const int t   = threadIdx.x;
    const int l   = t & 63;
    const int g   = t >> 6;               // wave 0..15
    const int hw0 = blockIdx.x * 256;
    const int ch  = blockIdx.y;           // c-half 0/1
    const int n   = blockIdx.z;

    if (ch == 0 && t < 256) {             // fused geo for this block's pixels
        const int px = n * HW_ + hw0 + t;
        const float* b = bb + (size_t)px * 5;
        const float cx = b[0], cy = b[1], bw = b[2], bh = b[3], th = b[4];
        const float st = sinf(th), ct = cosf(th);
        const float vx = bw * ct * 0.5f, vy = bw * st * 0.5f;
        const float wx = -bh * st * 0.5f, wy = bh * ct * 0.5f;
        const float pxs[5] = {cx, cx + vx + wx, cx - vx + wx, cx - vx - wx, cx + vx - wx};
        const float pys[5] = {cy, cy + vy + wy, cy - vy + wy, cy - vy - wy, cy + vy - wy};
        uint32* gw = geoG + (size_t)px * 32;
#pragma unroll
        for (int p = 0; p < 5; ++p) {
            float x = pxs[p] * SCALE;
            float y = pys[p] * SCALE;
            const bool valid = (y >= -1.0f) && (y <= (float)H_) &&
                               (x >= -1.0f) && (x <= (float)W_);
            y = fmaxf(y, 0.0f);
            x = fmaxf(x, 0.0f);
            int yl = min((int)y, H_ - 1);
            int xl = min((int)x, W_ - 1);
            if (yl >= H_ - 1) y = (float)yl;   // mmcv border snap: ly = 0
            if (xl >= W_ - 1) x = (float)xl;   // lx = 0
            const int yh = min(yl + 1, H_ - 1);
            const float ly = y - (float)yl, lx = x - (float)xl;
            const float hy = 1.0f - ly,     hx = 1.0f - lx;
            const int xa = min(xl, W_ - 2);
            float wA, wB;
            if (xl < W_ - 1) { wA = hx; wB = lx; }
            else             { wA = 0.0f; wB = 1.0f; }
            const float v = valid ? 1.0f : 0.0f;
            gw[p]      = (uint32)(yl * W_ + xa);
            gw[5 + p]  = (uint32)(yh * W_ + xa);
            gw[10 + p] = __float_as_uint(v * hy * wA);
            gw[15 + p] = __float_as_uint(v * hy * wB);
            gw[20 + p] = __float_as_uint(v * ly * wA);
            gw[25 + p] = __float_as_uint(v * ly * wB);
        }
        gw[30] = 0u; gw[31] = 0u;
    }

    // channels of this half: ch*128 + 2cp, 2cp+1 for cp = 0..63
    const float* base = in + (size_t)n * C_ * HW_ + (size_t)(ch * 128) * HW_ + hw0 + 4 * l;
    float4 v0[4], v1[4];
#pragma unroll
    for (int r = 0; r < 4; ++r) {
        const int cp = g * 4 + r;
        v0[r] = *(const float4*)(base + (size_t)(2 * cp) * HW_);
        v1[r] = *(const float4*)(base + (size_t)(2 * cp + 1) * HW_);
    }
#pragma unroll
    for (int r = 0; r < 4; ++r) {
        const int cp = g * 4 + r;
        uint4 u;
        u.x = f2bf(v0[r].x) | (f2bf(v1[r].x) << 16);
        u.y = f2bf(v0[r].y) | (f2bf(v1[r].y) << 16);
        u.z = f2bf(v0[r].z) | (f2bf(v1[r].z) << 16);
        u.w = f2bf(v0[r].w) | (f2bf(v1[r].w) << 16);
        *(uint4*)&tile[cp * 260 + 4 * l] = u;   // b128, conflict-free
    }
    __syncthreads();
    // NHWC word layout: word w of pixel = channels (2w, 2w+1); this half owns
    // words ch*64 .. ch*64+63 of each pixel row (128 words).
    uint32* dst = outU + ((size_t)n * HW_ + hw0) * 128 + ch * 64;
#pragma unroll
    for (int it = 0; it < 16; ++it) {
        const int f   = it * 1024 + t;    // f = row*64 + q
        const int row = f >> 6;
        const int q   = f & 63;
        dst[(size_t)row * 128 + q] = tile[q * 260 + row];   // 8-way LDS, ~0.1us
    }
}

// ---------- Pass 1: refine v3 — wave per pixel, channel-split, full occupancy ----------
// Block: 256 thr, 32 px x 128 ch (c-half from XCD id). Gathers are uint2
// (8B/lane): lanes 0-31 cover corner-x A (all 128 ch of the half), lanes
// 32-63 corner-x B (next pixel row). 11 loads pinned in flight per p via
// sched_barrier(0). LDS 16KB + <=64 VGPR -> 8 blocks/CU.
__global__ __launch_bounds__(256, 8) void fr_refine(const uint32* __restrict__ nhwcU,
                                                    const uint32* __restrict__ geoG,
                                                    float* __restrict__ out)
{
    __shared__ float tile[32 * 128];      // [px][c] fp32, XOR-swizzled, 16 KB
    const int t  = threadIdx.x;
    const int l  = t & 63;
    const int wv = __builtin_amdgcn_readfirstlane(t >> 6);
    const int bx = blockIdx.x;            // [0, 4096)
    // XCD (bx&7) = (batch, c-half): per-XCD gather set = 4MB half-channel
    // plane = exactly one L2. (Gathers are RANDOM over the plane — cx,cy are
    // uniform over the image — so only c-splitting, not pixel placement,
    // shrinks the working set.)
    const int xcd = bx & 7;
    const int n   = xcd >> 1;
    const int ch  = xcd & 1;
    const int s   = bx >> 3;              // [0, 512) = 128 h x 4 w-tiles
    const int h   = s >> 2;
    const int w0  = (s & 3) * 32;

    const int lh = l >> 5;                // 0: corner A, 1: corner B (next px)
    const int lw = l & 31;
    const int lofs = (lh << 7) + (ch << 6) + (lw << 1);   // words from row start
    const float idsel = lh ? 0.0f : 1.0f;
    const uint32* plane = nhwcU + (size_t)n * HW_ * 128;
    const int hwb = h * W_ + w0 + wv * 8;
    const uint32* gb = geoG + ((size_t)n * HW_ + hwb) * 32;

#pragma unroll 1
    for (int p = 0; p < 8; ++p) {
        const uint32* g = gb + p * 32;    // wave-uniform -> s_load

        // scalar geo: offsets + weights first (SGPRs, no vmem dependence)
        int o0[5], o1[5];
        float wr0[5], wr1[5];
#pragma unroll
        for (int q = 0; q < 5; ++q) {
            o0[q] = (int)g[q];
            o1[q] = (int)g[5 + q];
            wr0[q] = lh ? __uint_as_float(g[15 + q]) : __uint_as_float(g[10 + q]);
            wr1[q] = lh ? __uint_as_float(g[25 + q]) : __uint_as_float(g[20 + q]);
        }

        // ---- issue ALL 11 row loads, then fence so they can't sink ----
        const uint2 rid = *(const uint2*)(plane + (size_t)(hwb + p) * 128 + lofs);
        uint2 r0[5], r1[5];
#pragma unroll
        for (int q = 0; q < 5; ++q) {
            r0[q] = *(const uint2*)(plane + (size_t)o0[q] * 128 + lofs);
            r1[q] = *(const uint2*)(plane + (size_t)o1[q] * 128 + lofs);
        }
        __builtin_amdgcn_sched_barrier(0);

        float a[4];
        a[0] = idsel * blo(rid.x); a[1] = idsel * bhi(rid.x);
        a[2] = idsel * blo(rid.y); a[3] = idsel * bhi(rid.y);
#pragma unroll
        for (int q = 0; q < 5; ++q) {
            a[0] = fmaf(wr0[q], blo(r0[q].x), a[0]);
            a[1] = fmaf(wr0[q], bhi(r0[q].x), a[1]);
            a[2] = fmaf(wr0[q], blo(r0[q].y), a[2]);
            a[3] = fmaf(wr0[q], bhi(r0[q].y), a[3]);
            a[0] = fmaf(wr1[q], blo(r1[q].x), a[0]);
            a[1] = fmaf(wr1[q], bhi(r1[q].x), a[1]);
            a[2] = fmaf(wr1[q], blo(r1[q].y), a[2]);
            a[3] = fmaf(wr1[q], bhi(r1[q].y), a[3]);
        }
        // combine corner-x halves; lanes 0-31 hold channels 4*lw..4*lw+3
#pragma unroll
        for (int k = 0; k < 4; ++k) a[k] += __shfl_xor(a[k], 32, 64);
        if (l < 32) {
            const int px = wv * 8 + p;
            const int c0 = (lw * 4) ^ ((px & 7) << 2);   // XOR swizzle, b128-safe
            *(float4*)&tile[px * 128 + c0] = make_float4(a[0], a[1], a[2], a[3]);
        }
    }
    __syncthreads();
    // epilogue: [32px][128c] -> NCHW; swizzled read is 4-way (~free)
    const size_t obase = (size_t)n * C_ * HW_ + (size_t)(ch * 128) * HW_ + h * W_ + w0;
#pragma unroll
    for (int it = 0; it < 16; ++it) {
        const int flat = it * 256 + t;
        const int px = flat & 31;
        const int c  = flat >> 5;          // 0..127
        out[obase + (size_t)c * HW_ + px] = tile[px * 128 + (c ^ ((px & 7) << 2))];
    }
}

// ---------- Fallback (round-1 kernel) if ws too small ----------
__global__ __launch_bounds__(256) void fr_kernel(
    const float* __restrict__ feat,
    const float* __restrict__ bb,
    float* __restrict__ out)
{
    const int lane = threadIdx.x & 63;
    const int wave = threadIdx.x >> 6;
    const int tile = blockIdx.x;
    const int wt   = tile & 1;
    const int h    = (tile >> 1) & (H_ - 1);
    const int n    = tile >> 8;
    const int w    = wt * 64 + lane;
    const int cb   = blockIdx.y;

    const float* b = bb + (size_t)((n * H_ + h) * W_ + w) * 5;
    const float cx = b[0], cy = b[1], bw = b[2], bh = b[3], th = b[4];
    const float st = sinf(th), ct = cosf(th);
    const float vx = bw * ct * 0.5f, vy = bw * st * 0.5f;
    const float wx = -bh * st * 0.5f, wy = bh * ct * 0.5f;
    const float pxs[5] = {cx, cx + vx + wx, cx - vx + wx, cx - vx - wx, cx + vx - wx};
    const float pys[5] = {cy, cy + vy + wy, cy - vy + wy, cy - vy - wy, cy + vy - wy};

    int   off0[5], off1[5];
    float wgt[20];
#pragma unroll
    for (int p = 0; p < 5; ++p) {
        float x = pxs[p] * SCALE;
        float y = pys[p] * SCALE;
        const bool valid = (y >= -1.0f) && (y <= (float)H_) &&
                           (x >= -1.0f) && (x <= (float)W_);
        y = fmaxf(y, 0.0f);
        x = fmaxf(x, 0.0f);
        int yl = min((int)y, H_ - 1);
        int xl = min((int)x, W_ - 1);
        if (yl >= H_ - 1) y = (float)yl;
        if (xl >= W_ - 1) x = (float)xl;
        const int yh = min(yl + 1, H_ - 1);
        const float ly = y - (float)yl, lx = x - (float)xl;
        const float hy = 1.0f - ly,     hx = 1.0f - lx;
        const int xa = min(xl, W_ - 2);
        float wA, wB;
        if (xl < W_ - 1) { wA = hx; wB = lx; }
        else             { wA = 0.0f; wB = 1.0f; }
        const float v = valid ? 1.0f : 0.0f;
        off0[p] = yl * W_ + xa;
        off1[p] = yh * W_ + xa;
        wgt[p * 4 + 0] = v * hy * wA;
        wgt[p * 4 + 1] = v * hy * wB;
        wgt[p * 4 + 2] = v * ly * wA;
        wgt[p * 4 + 3] = v * ly * wB;
    }

    const int hw = h * W_ + w;
    const size_t planeBase = ((size_t)n * C_ + cb * 64 + wave * 16) * HW_;
    const float* fp = feat + planeBase;
    float*       op = out  + planeBase;
    for (int it = 0; it < 16; ++it) {
        float acc = fp[hw];
#pragma unroll
        for (int p = 0; p < 5; ++p) {
            acc += wgt[p * 4 + 0] * fp[off0[p]]
                 + wgt[p * 4 + 1] * fp[off0[p] + 1]
                 + wgt[p * 4 + 2] * fp[off1[p]]
                 + wgt[p * 4 + 3] * fp[off1[p] + 1];
        }
        op[hw] = acc;
        fp += HW_;
        op += HW_;
    }
}

extern "C" void kernel_launch(void* const* d_in, const int* in_sizes, int n_in,
                              void* d_out, int out_size, void* d_ws, size_t ws_size,
                              hipStream_t stream) {
    const float* feat = (const float*)d_in[0];   // [N,C,H,W] fp32
    const float* bbox = (const float*)d_in[1];   // [N,H,W,5] fp32
    float* out = (float*)d_out;

    const size_t nhwcBytes = (size_t)N_ * HW_ * C_ * 2;        // 32 MB bf16
    const size_t geoBytes  = (size_t)N_ * HW_ * 32 * 4;        // 8 MB
    if (ws_size >= nhwcBytes + geoBytes) {
        uint32* nhwcU = (uint32*)d_ws;                         // keep geo AFTER
        uint32* geoG  = (uint32*)((char*)d_ws + nhwcBytes);    // nhwc: absorbs
                                                               // tail OOB reads
        nchw2nhwc_geo<<<dim3(HW_ / 256, 2, N_), dim3(1024), 0, stream>>>(feat, bbox, nhwcU, geoG);
        fr_refine<<<dim3(N_ * H_ * (W_ / 32) * 2), dim3(256), 0, stream>>>(nhwcU, geoG, out);
    } else {
        dim3 grid(N_ * H_ * (W_ / 64), C_ / 64, 1);
        fr_kernel<<<grid, dim3(256), 0, stream>>>(feat, bbox, out);
    }
}

// Round 3
// 158.582 us; speedup vs baseline: 1.1413x; 1.1413x over previous
//
#include <hip/hip_runtime.h>

// FeatureRefine, MI355X/gfx950 — round 8.
// R7 post-mortem: c-split worked for L2 (FETCH 201->114MB, occ 35->71%) but
// dur 67.5->76us: gather instruction count doubled (22/px, 2x256B segments)
// and VGPR=32 broke per-wave MLP (~5 loads in flight). => bound on the
// vector-memory request path, not latency alone.
// R8: 4-corner-per-load gathers. One 64-lane x 16B load covers all 4 bilinear
// corners of one point (4 x 256B segments: rows {yl,yh} x pixels {xa,xa+1},
// one c-half). 5 gathers + 1 masked identity = 6 inst/px/c-half (12/px total,
// vs 22 in R7), zero wasted bytes, full MLP=6 (24 VGPRs payload), corner
// reduce = 2 butterfly shuffles. Geo via readfirstlane -> SGPR. LDS 16KB,
// launch_bounds(256,8) -> target 8 blocks/CU.

#define N_ 4
#define C_ 256
#define H_ 128
#define W_ 128
#define HW_ (H_ * W_)
#define SCALE 0.125f

typedef unsigned int uint32;

__device__ __forceinline__ uint32 f2bf(float f) {
    uint32 u = __float_as_uint(f);
    u = (u + 0x7FFF + ((u >> 16) & 1)) >> 16;   // RNE
    return u;
}
__device__ __forceinline__ float blo(uint32 u) { return __uint_as_float(u << 16); }
__device__ __forceinline__ float bhi(uint32 u) { return __uint_as_float(u & 0xFFFF0000u); }

// ---------- Pass 0: NCHW fp32 -> NHWC bf16 (packed ch-pairs) + fused geo ----------
// Tile 256 hw x 128 ch (one c-half). 1024 thr / 16 waves; 4 cpairs per wave.
// LDS [64 cpair][256 hw + pad] = 66.5 KB -> 2 blocks/CU (phases overlap).
__global__ __launch_bounds__(1024, 8) void nchw2nhwc_geo(const float* __restrict__ in,
                                                         const float* __restrict__ bb,
                                                         uint32* __restrict__ outU,
                                                         uint32* __restrict__ geoG)
{
    __shared__ uint32 tile[64 * 260];
    const int t   = threadIdx.x;
    const int l   = t & 63;
    const int g   = t >> 6;               // wave 0..15
    const int hw0 = blockIdx.x * 256;
    const int ch  = blockIdx.y;           // c-half 0/1
    const int n   = blockIdx.z;

    if (ch == 0 && t < 256) {             // fused geo for this block's pixels
        const int px = n * HW_ + hw0 + t;
        const float* b = bb + (size_t)px * 5;
        const float cx = b[0], cy = b[1], bw = b[2], bh = b[3], th = b[4];
        const float st = sinf(th), ct = cosf(th);
        const float vx = bw * ct * 0.5f, vy = bw * st * 0.5f;
        const float wx = -bh * st * 0.5f, wy = bh * ct * 0.5f;
        const float pxs[5] = {cx, cx + vx + wx, cx - vx + wx, cx - vx - wx, cx + vx - wx};
        const float pys[5] = {cy, cy + vy + wy, cy - vy + wy, cy - vy - wy, cy + vy - wy};
        uint32* gw = geoG + (size_t)px * 32;
#pragma unroll
        for (int p = 0; p < 5; ++p) {
            float x = pxs[p] * SCALE;
            float y = pys[p] * SCALE;
            const bool valid = (y >= -1.0f) && (y <= (float)H_) &&
                               (x >= -1.0f) && (x <= (float)W_);
            y = fmaxf(y, 0.0f);
            x = fmaxf(x, 0.0f);
            int yl = min((int)y, H_ - 1);
            int xl = min((int)x, W_ - 1);
            if (yl >= H_ - 1) y = (float)yl;   // mmcv border snap: ly = 0
            if (xl >= W_ - 1) x = (float)xl;   // lx = 0
            const int yh = min(yl + 1, H_ - 1);
            const float ly = y - (float)yl, lx = x - (float)xl;
            const float hy = 1.0f - ly,     hx = 1.0f - lx;
            const int xa = min(xl, W_ - 2);
            float wA, wB;
            if (xl < W_ - 1) { wA = hx; wB = lx; }
            else             { wA = 0.0f; wB = 1.0f; }
            const float v = valid ? 1.0f : 0.0f;
            gw[p]      = (uint32)(yl * W_ + xa);
            gw[5 + p]  = (uint32)(yh * W_ + xa);
            gw[10 + p] = __float_as_uint(v * hy * wA);
            gw[15 + p] = __float_as_uint(v * hy * wB);
            gw[20 + p] = __float_as_uint(v * ly * wA);
            gw[25 + p] = __float_as_uint(v * ly * wB);
        }
        gw[30] = 0u; gw[31] = 0u;
    }

    // channels of this half: ch*128 + 2cp, 2cp+1 for cp = 0..63
    const float* base = in + (size_t)n * C_ * HW_ + (size_t)(ch * 128) * HW_ + hw0 + 4 * l;
    float4 v0[4], v1[4];
#pragma unroll
    for (int r = 0; r < 4; ++r) {
        const int cp = g * 4 + r;
        v0[r] = *(const float4*)(base + (size_t)(2 * cp) * HW_);
        v1[r] = *(const float4*)(base + (size_t)(2 * cp + 1) * HW_);
    }
#pragma unroll
    for (int r = 0; r < 4; ++r) {
        const int cp = g * 4 + r;
        uint4 u;
        u.x = f2bf(v0[r].x) | (f2bf(v1[r].x) << 16);
        u.y = f2bf(v0[r].y) | (f2bf(v1[r].y) << 16);
        u.z = f2bf(v0[r].z) | (f2bf(v1[r].z) << 16);
        u.w = f2bf(v0[r].w) | (f2bf(v1[r].w) << 16);
        *(uint4*)&tile[cp * 260 + 4 * l] = u;   // b128, conflict-free
    }
    __syncthreads();
    // NHWC word layout: word w of pixel = channels (2w, 2w+1); this half owns
    // words ch*64 .. ch*64+63 of each pixel row (128 words).
    uint32* dst = outU + ((size_t)n * HW_ + hw0) * 128 + ch * 64;
#pragma unroll
    for (int it = 0; it < 16; ++it) {
        const int f   = it * 1024 + t;    // f = row*64 + q
        const int row = f >> 6;
        const int q   = f & 63;
        dst[(size_t)row * 128 + q] = tile[q * 260 + row];
    }
}

// ---------- Pass 1: refine v4 — 4-corner-per-load gathers ----------
// Block: 256 thr, 32 px x 128 ch (c-half from XCD id). Per point, ONE
// 64-lane x 16B load covers all 4 bilinear corners (4 x 256B segments):
// lane group l>>4: 0=(yl,xa) 1=(yl,xa+1) 2=(yh,xa) 3=(yh,xa+1), 8 channels
// per lane. 5 gathers + masked identity = 6 loads/px in flight
// (sched_barrier pins them). Corner reduce: shfl_xor 16 then 32.
__global__ __launch_bounds__(256, 8) void fr_refine(const uint32* __restrict__ nhwcU,
                                                    const uint32* __restrict__ geoG,
                                                    float* __restrict__ out)
{
    __shared__ float tile[32 * 128];      // [px][c] fp32, XOR-swizzled, 16 KB
    const int t  = threadIdx.x;
    const int l  = t & 63;
    const int wv = __builtin_amdgcn_readfirstlane(t >> 6);
    const int bx = blockIdx.x;            // [0, 4096)
    // XCD (bx&7) = (batch, c-half): per-XCD gather set = 4MB = one L2.
    const int xcd = bx & 7;
    const int n   = xcd >> 1;
    const int ch  = xcd & 1;
    const int s   = bx >> 3;              // [0, 512) = 128 h x 4 w-tiles
    const int h   = s >> 2;
    const int w0  = (s & 3) * 32;

    const int chB = ch << 8;              // byte offset of c-half in 512B px row
    // per-lane constant: 16B slot within 256B segment + corner-B (+512B = next px)
    const int laneb = ((l & 15) << 4) + (((l >> 4) & 1) << 9);
    const bool hi = (l >= 32);            // rows yh (corners 2,3)
    const bool b4 = ((l >> 4) & 1) != 0;  // corner-B within row
    const int hwb = h * W_ + w0 + wv * 8;
    const uint32* gb = geoG + ((size_t)n * HW_ + hwb) * 32;
    const char* plane = (const char*)(nhwcU + (size_t)n * HW_ * 128);

#pragma unroll 1
    for (int p = 0; p < 8; ++p) {
        const uint32* g = gb + p * 32;

        // scalar geo -> SGPRs (wave-uniform)
        int o0b[5], o1b[5];
        float w00[5], w01[5], w10[5], w11[5];
#pragma unroll
        for (int q = 0; q < 5; ++q) {
            o0b[q] = (int)__builtin_amdgcn_readfirstlane(g[q])     * 512 + chB;
            o1b[q] = (int)__builtin_amdgcn_readfirstlane(g[5 + q]) * 512 + chB;
            w00[q] = __uint_as_float(__builtin_amdgcn_readfirstlane(g[10 + q]));
            w01[q] = __uint_as_float(__builtin_amdgcn_readfirstlane(g[15 + q]));
            w10[q] = __uint_as_float(__builtin_amdgcn_readfirstlane(g[20 + q]));
            w11[q] = __uint_as_float(__builtin_amdgcn_readfirstlane(g[25 + q]));
        }

        // ---- issue all 6 loads, then fence so they can't sink ----
        uint4 rid = make_uint4(0u, 0u, 0u, 0u);
        if (l < 16)
            rid = *(const uint4*)(plane + (size_t)(hwb + p) * 512 + chB + ((l & 15) << 4));
        uint4 r[5];
#pragma unroll
        for (int q = 0; q < 5; ++q) {
            const int vof = (hi ? o1b[q] : o0b[q]) + laneb;
            r[q] = *(const uint4*)(plane + vof);
        }
        __builtin_amdgcn_sched_barrier(0);

        float a[8];
        a[0] = blo(rid.x); a[1] = bhi(rid.x);
        a[2] = blo(rid.y); a[3] = bhi(rid.y);
        a[4] = blo(rid.z); a[5] = bhi(rid.z);
        a[6] = blo(rid.w); a[7] = bhi(rid.w);
#pragma unroll
        for (int q = 0; q < 5; ++q) {
            const float wq = hi ? (b4 ? w11[q] : w10[q]) : (b4 ? w01[q] : w00[q]);
            a[0] = fmaf(wq, blo(r[q].x), a[0]); a[1] = fmaf(wq, bhi(r[q].x), a[1]);
            a[2] = fmaf(wq, blo(r[q].y), a[2]); a[3] = fmaf(wq, bhi(r[q].y), a[3]);
            a[4] = fmaf(wq, blo(r[q].z), a[4]); a[5] = fmaf(wq, bhi(r[q].z), a[5]);
            a[6] = fmaf(wq, blo(r[q].w), a[6]); a[7] = fmaf(wq, bhi(r[q].w), a[7]);
        }
        // sum the 4 corner groups (butterfly: every lane gets the total)
#pragma unroll
        for (int k = 0; k < 8; ++k) {
            a[k] += __shfl_xor(a[k], 16, 64);
            a[k] += __shfl_xor(a[k], 32, 64);
        }
        if (l < 16) {                      // lanes 0-15 hold ch 8l..8l+7
            const int px  = wv * 8 + p;
            const int swz = (px & 7) << 2;
            float* base = &tile[px * 128];
            *(float4*)&base[(l * 8) ^ swz]     = make_float4(a[0], a[1], a[2], a[3]);
            *(float4*)&base[(l * 8 + 4) ^ swz] = make_float4(a[4], a[5], a[6], a[7]);
        }
    }
    __syncthreads();
    // epilogue: [32px][128c] -> NCHW; swizzled read is 4-way (~free)
    const size_t obase = (size_t)n * C_ * HW_ + (size_t)(ch * 128) * HW_ + h * W_ + w0;
#pragma unroll
    for (int it = 0; it < 16; ++it) {
        const int flat = it * 256 + t;
        const int px = flat & 31;
        const int c  = flat >> 5;          // 0..127
        out[obase + (size_t)c * HW_ + px] = tile[px * 128 + (c ^ ((px & 7) << 2))];
    }
}

// ---------- Fallback (round-1 kernel) if ws too small ----------
__global__ __launch_bounds__(256) void fr_kernel(
    const float* __restrict__ feat,
    const float* __restrict__ bb,
    float* __restrict__ out)
{
    const int lane = threadIdx.x & 63;
    const int wave = threadIdx.x >> 6;
    const int tile = blockIdx.x;
    const int wt   = tile & 1;
    const int h    = (tile >> 1) & (H_ - 1);
    const int n    = tile >> 8;
    const int w    = wt * 64 + lane;
    const int cb   = blockIdx.y;

    const float* b = bb + (size_t)((n * H_ + h) * W_ + w) * 5;
    const float cx = b[0], cy = b[1], bw = b[2], bh = b[3], th = b[4];
    const float st = sinf(th), ct = cosf(th);
    const float vx = bw * ct * 0.5f, vy = bw * st * 0.5f;
    const float wx = -bh * st * 0.5f, wy = bh * ct * 0.5f;
    const float pxs[5] = {cx, cx + vx + wx, cx - vx + wx, cx - vx - wx, cx + vx - wx};
    const float pys[5] = {cy, cy + vy + wy, cy - vy + wy, cy - vy - wy, cy + vy - wy};

    int   off0[5], off1[5];
    float wgt[20];
#pragma unroll
    for (int p = 0; p < 5; ++p) {
        float x = pxs[p] * SCALE;
        float y = pys[p] * SCALE;
        const bool valid = (y >= -1.0f) && (y <= (float)H_) &&
                           (x >= -1.0f) && (x <= (float)W_);
        y = fmaxf(y, 0.0f);
        x = fmaxf(x, 0.0f);
        int yl = min((int)y, H_ - 1);
        int xl = min((int)x, W_ - 1);
        if (yl >= H_ - 1) y = (float)yl;
        if (xl >= W_ - 1) x = (float)xl;
        const int yh = min(yl + 1, H_ - 1);
        const float ly = y - (float)yl, lx = x - (float)xl;
        const float hy = 1.0f - ly,     hx = 1.0f - lx;
        const int xa = min(xl, W_ - 2);
        float wA, wB;
        if (xl < W_ - 1) { wA = hx; wB = lx; }
        else             { wA = 0.0f; wB = 1.0f; }
        const float v = valid ? 1.0f : 0.0f;
        off0[p] = yl * W_ + xa;
        off1[p] = yh * W_ + xa;
        wgt[p * 4 + 0] = v * hy * wA;
        wgt[p * 4 + 1] = v * hy * wB;
        wgt[p * 4 + 2] = v * ly * wA;
        wgt[p * 4 + 3] = v * ly * wB;
    }

    const int hw = h * W_ + w;
    const size_t planeBase = ((size_t)n * C_ + cb * 64 + wave * 16) * HW_;
    const float* fp = feat + planeBase;
    float*       op = out  + planeBase;
    for (int it = 0; it < 16; ++it) {
        float acc = fp[hw];
#pragma unroll
        for (int p = 0; p < 5; ++p) {
            acc += wgt[p * 4 + 0] * fp[off0[p]]
                 + wgt[p * 4 + 1] * fp[off0[p] + 1]
                 + wgt[p * 4 + 2] * fp[off1[p]]
                 + wgt[p * 4 + 3] * fp[off1[p] + 1];
        }
        op[hw] = acc;
        fp += HW_;
        op += HW_;
    }
}

extern "C" void kernel_launch(void* const* d_in, const int* in_sizes, int n_in,
                              void* d_out, int out_size, void* d_ws, size_t ws_size,
                              hipStream_t stream) {
    const float* feat = (const float*)d_in[0];   // [N,C,H,W] fp32
    const float* bbox = (const float*)d_in[1];   // [N,H,W,5] fp32
    float* out = (float*)d_out;

    const size_t nhwcBytes = (size_t)N_ * HW_ * C_ * 2;        // 32 MB bf16
    const size_t geoBytes  = (size_t)N_ * HW_ * 32 * 4;        // 8 MB
    if (ws_size >= nhwcBytes + geoBytes) {
        uint32* nhwcU = (uint32*)d_ws;
        uint32* geoG  = (uint32*)((char*)d_ws + nhwcBytes);
        nchw2nhwc_geo<<<dim3(HW_ / 256, 2, N_), dim3(1024), 0, stream>>>(feat, bbox, nhwcU, geoG);
        fr_refine<<<dim3(N_ * H_ * (W_ / 32) * 2), dim3(256), 0, stream>>>(nhwcU, geoG, out);
    } else {
        dim3 grid(N_ * H_ * (W_ / 64), C_ / 64, 1);
        fr_kernel<<<grid, dim3(256), 0, stream>>>(feat, bbox, out);
    }
}